// Round 10
// baseline (279.315 us; speedup 1.0000x reference)
//
#include <hip/hip_runtime.h>
#include <hip/hip_bf16.h>
#include <cstddef>
#include <cstdint>

#define BB 32
#define NN 4096
#define KK 8
#define DD 256
#define HH 512
#define LN_EPS 1e-5f
#define SCALE 0.0625f  // 1/sqrt(256)
#define NCHUNK 32      // attn partial chunks per batch (512 blocks x 2 halves)

__device__ __forceinline__ float wave_sum(float v) {
#pragma unroll
  for (int off = 32; off >= 1; off >>= 1) v += __shfl_xor(v, off);
  return v;
}

__device__ __forceinline__ float sigmoidf_(float x) { return 1.0f / (1.0f + __expf(-x)); }

__device__ __forceinline__ uint pk2bf(float x, float y) {
  __hip_bfloat16 hx = __float2bfloat16(x), hy = __float2bfloat16(y);
  return (uint)*(ushort*)&hx | ((uint)*(ushort*)&hy << 16);
}

// packed bf16 weight pool offsets (elements).
// layout per matrix (OUT outputs, K inputs): elem(k,j) at (k>>2)*OUT*4 + j*4 + (k&3)
#define OFF_G   0        // 6 gate matrices [ih_r,ih_z,ih_n,hh_r,hh_z,hh_n], 65536 each
#define OFF_W1  393216   // OUT=512 K=256
#define OFF_W2  524288   // OUT=256 K=512
#define OFF_WV  655360   // OUT=256 K=256 (columns pre-scaled by ln_in_g)
#define OFF_WQ  720896   // OUT=256 K=256
#define OFF_WK  786432   // OUT=256(j) K=256(d), src Wk[d*256+j]
#define WB_ELEMS 851968

#define G_PRE (BB * KK)              // 256
#define G_W2B (512 * 11)             // 5632
#define G_SETUP (G_PRE + G_W2B + 1)  // +1 block for bv' = bv + Wv.b

__device__ __forceinline__ float dotp4(uint2 w, float4 s) {
  return __uint_as_float(w.x << 16) * s.x + __uint_as_float(w.x & 0xffff0000u) * s.y +
         __uint_as_float(w.y << 16) * s.z + __uint_as_float(w.y & 0xffff0000u) * s.w;
}

// coalesced packed GEMV partial: output j, k in [kb, kb+KL)
template <int OUT, int KL>
__device__ __forceinline__ float gemv_p(const ushort* __restrict__ wt, int j, int kb,
                                        const float* __restrict__ src) {
  const uint2* p = (const uint2*)(wt + ((size_t)(kb >> 2) * OUT + j) * 4);
  float a = 0.0f;
#pragma unroll 16
  for (int e = 0; e < KL / 4; ++e) {
    uint2 w = p[(size_t)e * OUT];
    float4 s = *(const float4*)(src + kb + e * 4);
    a += dotp4(w, s);
  }
  return a;
}

// ---------- Kernel 1 (setup): slots_pre + w2b pack + bv' ----------
__global__ __launch_bounds__(256) void k_setup(
    const float* __restrict__ Wih, const float* __restrict__ Whh,
    const float* __restrict__ W1, const float* __restrict__ W2,
    const float* __restrict__ Wv, const float* __restrict__ Wq,
    const float* __restrict__ Wk, ushort* __restrict__ wb,
    const float* __restrict__ slots, const float* __restrict__ gs, const float* __restrict__ bs,
    const float* __restrict__ bq, const float* __restrict__ bk,
    const float* __restrict__ gi, const float* __restrict__ bi,
    const float* __restrict__ bv, float* __restrict__ bvw,
    float* __restrict__ qk, float* __restrict__ qb) {
  int blk = blockIdx.x;
  if (blk < G_PRE) {
    // ---- initial qk/qb from slots_init (fp32 weights), with g/b folded ----
    int row = blk;
    int t = threadIdx.x;
    int wid = t >> 6, lane = t & 63;
    __shared__ float lns[DD];
    __shared__ float qs[DD];
    __shared__ float rb[8];
    float sv = slots[(size_t)row * DD + t];
    float s = wave_sum(sv);
    float s2 = wave_sum(sv * sv);
    if (lane == 0) { rb[wid] = s; rb[4 + wid] = s2; }
    __syncthreads();
    float tot = rb[0] + rb[1] + rb[2] + rb[3];
    float tot2 = rb[4] + rb[5] + rb[6] + rb[7];
    float m = tot * (1.0f / DD);
    float var = tot2 * (1.0f / DD) - m * m;
    float rs = rsqrtf(var + LN_EPS);
    lns[t] = (sv - m) * rs * gs[t] + bs[t];
    __syncthreads();
    float acc = 0.0f;
    const float4* wr = (const float4*)(Wq + (size_t)t * DD);
#pragma unroll 4
    for (int e4 = 0; e4 < DD / 4; ++e4) {
      float4 w = wr[e4];
      float4 l = ((const float4*)lns)[e4];
      acc += w.x * l.x + w.y * l.y + w.z * l.z + w.w * l.w;
    }
    qs[t] = acc + bq[t];
    __syncthreads();
    float a2 = 0.0f;
    for (int d = 0; d < DD; ++d) a2 = fmaf(qs[d], Wk[(size_t)d * DD + t], a2);
    float a2S = SCALE * a2;
    qk[(size_t)row * DD + t] = a2S * gi[t];
    float pb = wave_sum(qs[t] * bk[t]);
    float pb2 = wave_sum(a2S * bi[t]);
    __syncthreads();
    if (lane == 0) { rb[wid] = pb; rb[4 + wid] = pb2; }
    __syncthreads();
    if (t == 0) qb[row] = SCALE * (rb[0] + rb[1] + rb[2] + rb[3]) + rb[4] + rb[5] + rb[6] + rb[7];
  } else if (blk < G_PRE + G_W2B) {
    // ---- pack weights to bf16 ----
    int q2 = blk - G_PRE;
    int m = q2 >> 9;             // /512
    int idx = (q2 & 511) * 256 + threadIdx.x;
    const int sizes[11] = {65536, 65536, 65536, 65536, 65536, 65536, 131072, 131072, 65536, 65536, 65536};
    const int offs[11] = {OFF_G, OFF_G + 65536, OFF_G + 131072, OFF_G + 196608, OFF_G + 262144,
                          OFF_G + 327680, OFF_W1, OFF_W2, OFF_WV, OFF_WQ, OFF_WK};
    if (idx >= sizes[m]) return;
    int K = (m == 7) ? 512 : 256;
    int OUT = (m == 6) ? 512 : 256;
    int k = idx % K, j = idx / K;
    float v;
    switch (m) {
      case 0: case 1: case 2: v = Wih[((size_t)(m * 256 + j)) * 256 + k]; break;
      case 3: case 4: case 5: v = Whh[((size_t)((m - 3) * 256 + j)) * 256 + k]; break;
      case 6: v = W1[(size_t)j * 256 + k]; break;
      case 7: v = W2[(size_t)j * 512 + k]; break;
      case 8: v = Wv[(size_t)j * 256 + k] * gi[k]; break;  // fold LN gamma
      case 9: v = Wq[(size_t)j * 256 + k]; break;
      default: v = Wk[(size_t)k * 256 + j]; break;
    }
    __hip_bfloat16 h = __float2bfloat16(v);
    wb[(size_t)offs[m] + (size_t)(k >> 2) * OUT * 4 + j * 4 + (k & 3)] = *(ushort*)&h;
  } else {
    // ---- bv' = bv + Wv . ln_in_b ----
    int t = threadIdx.x;
    float a = bv[t];
    const float4* wr = (const float4*)(Wv + (size_t)t * DD);
    const float4* bb = (const float4*)bi;
#pragma unroll 4
    for (int e4 = 0; e4 < DD / 4; ++e4) {
      float4 w = wr[e4];
      float4 x = bb[e4];
      a += w.x * x.x + w.y * x.y + w.z * x.z + w.w * x.w;
    }
    bvw[t] = a;
  }
}

// ---------- Kernel 3: MFMA attention, 512-thread / 2-chunk blocks ----------
// 8 waves = 2 halves; half h owns chunk c = (blk&15)*2+h with its own 16KB
// tile buffer; ONE shared q_l (8KB) per block. LDS = 8 + 2x16 = 40KB at 8
// waves -> 4 blocks/CU = 32 waves/CU (100% of wave cap).
// Per half per tile: barrier -> 4x global_load_lds per wave -> drain+barrier
// -> full QK (16 MFMA, redundant per wave) -> lane-local softmax -> AV (wave
// w4 owns dc 4*w4..4*w4+3, accumulators persist across tiles). Math
// bit-identical to the R8/R9-verified paths.
template <int DO_LN>
__global__ __launch_bounds__(512, 8) void k_attn_t(const ushort* __restrict__ xb_in,
                                                   ushort* __restrict__ xb_out,
                                                   const float* __restrict__ inp,
                                                   const float* __restrict__ qk,
                                                   const float* __restrict__ qb,
                                                   float* __restrict__ uxp,
                                                   float* __restrict__ sap) {
  typedef __attribute__((ext_vector_type(8))) short short8;
  typedef __attribute__((ext_vector_type(4))) float f32x4;
  union V16 { uint4 u; short8 s; ushort us[8]; };

  __shared__ __align__(16) ushort q_l[16 * 256];      // 8KB shared by both halves
  __shared__ __align__(16) ushort xtile[2][32 * 256]; // per-half 16KB tile buffer

  int t = threadIdx.x, wid = t >> 6, lane = t & 63;
  int h = wid >> 2, w4 = wid & 3, th = t & 255;
  int bI = blockIdx.x >> 4, c = ((blockIdx.x & 15) << 1) + h;
  int lm = lane & 15, g = lane >> 4;
  char* qB = (char*)q_l;
  ushort* xw = xtile[h];
  char* xwB = (char*)xw;

  // ---- stage q: threads <256 write hi planes 0-7, >=256 write lo planes 8-15 ----
  {
    const float* qkb = qk + (size_t)bI * (KK * DD);
    int p = th >> 3, e7 = th & 7;
    bool lohalf = t >= 256;
#pragma unroll 1
    for (int s = 0; s < 8; ++s) {
      float qv = qkb[s * 256 + th];
      __hip_bfloat16 hb = __float2bfloat16(qv);
      ushort st;
      if (!lohalf) {
        st = *(ushort*)&hb;
      } else {
        float lo = qv - __bfloat162float(hb);
        __hip_bfloat16 lb = __float2bfloat16(lo);
        st = *(ushort*)&lb;
      }
      int sr = lohalf ? (s + 8) : s;
      *(ushort*)(qB + sr * 512 + (((p + sr) & 31) << 4) + e7 * 2) = st;
    }
  }
  float qbv = qb[bI * 8 + (lane & 7)];

  f32x4 avacc[4];
#pragma unroll
  for (int i = 0; i < 4; ++i) avacc[i] = (f32x4){0.0f, 0.0f, 0.0f, 0.0f};
  float stot = 0.0f;

#pragma unroll 1
  for (int tt = 0; tt < 4; ++tt) {
    int row0 = c * 128 + tt * 32;
    __syncthreads();  // prev tile consumed by all waves (and q_l ready at tt=0)

    if (DO_LN) {
      int q8 = th & 7, rr = th >> 3;
      const float* rp = inp + ((size_t)bI * NN + row0 + rr) * DD + q8 * 4;
      float4 cur[8];
#pragma unroll
      for (int i = 0; i < 8; ++i) cur[i] = *(const float4*)(rp + i * 32);
      float s1 = 0.0f, s2 = 0.0f;
#pragma unroll
      for (int i = 0; i < 8; ++i) {
        s1 += cur[i].x + cur[i].y + cur[i].z + cur[i].w;
        s2 += cur[i].x * cur[i].x + cur[i].y * cur[i].y + cur[i].z * cur[i].z + cur[i].w * cur[i].w;
      }
      s1 += __shfl_xor(s1, 1); s2 += __shfl_xor(s2, 1);
      s1 += __shfl_xor(s1, 2); s2 += __shfl_xor(s2, 2);
      s1 += __shfl_xor(s1, 4); s2 += __shfl_xor(s2, 4);
      float m = s1 * (1.0f / DD);
      float var = s2 * (1.0f / DD) - m * m;
      float rs = rsqrtf(var + LN_EPS);
      int pb = q8 >> 1, hb8 = (q8 & 1) * 8;
#pragma unroll
      for (int i = 0; i < 8; ++i) {
        uint2 wv;
        wv.x = pk2bf((cur[i].x - m) * rs, (cur[i].y - m) * rs);
        wv.y = pk2bf((cur[i].z - m) * rs, (cur[i].w - m) * rs);
        *(uint2*)(xwB + ((4 * i + pb) << 9) + (rr << 4) + hb8) = wv;
      }
      __syncthreads();  // tile image complete
      ushort* xbt = xb_out + ((size_t)bI * NN + row0) * DD;
#pragma unroll
      for (int i = 0; i < 4; ++i)
        *(uint4*)((char*)xbt + i * 4096 + th * 16) = *(const uint4*)(xwB + i * 4096 + th * 16);
    } else {
      const ushort* srcb = xb_in + ((size_t)bI * NN + row0) * DD;
#pragma unroll
      for (int i = 0; i < 4; ++i) {
        __builtin_amdgcn_global_load_lds(
            (__attribute__((address_space(1))) void*)(srcb + i * 2048 + w4 * 512 + lane * 8),
            (__attribute__((address_space(3))) void*)(xw + i * 2048 + w4 * 512), 16, 0, 0);
      }
      asm volatile("s_waitcnt vmcnt(0) lgkmcnt(0)" ::: "memory");
      __builtin_amdgcn_sched_barrier(0);
      __syncthreads();  // all waves' loads landed
    }

    // ---------------- QK full (16 MFMAs, redundant per wave) ----------------
    int rA = lm, rB = lm + 16;
    f32x4 ac0 = {}, ac1 = {};
#pragma unroll
    for (int kk = 0; kk < 8; ++kk) {
      V16 qf, x0, x1;
      int ch = kk * 4 + g;
      qf.u = *(const uint4*)(qB + (lm << 9) + (((ch + lm) & 31) << 4));
      x0.u = *(const uint4*)(xwB + (ch << 9) + (rA << 4));
      x1.u = *(const uint4*)(xwB + (ch << 9) + (rB << 4));
      ac0 = __builtin_amdgcn_mfma_f32_16x16x32_bf16(x0.s, qf.s, ac0, 0, 0, 0);
      ac1 = __builtin_amdgcn_mfma_f32_16x16x32_bf16(x1.s, qf.s, ac1, 0, 0, 0);
    }

    // ---------------- softmax over slots (lane octet), rows vectorized ----------------
    float a0[4], a1[4];
    {
      float lv0[4], lv1[4], mx0[4], mx1[4], ss0[4], ss1[4];
#pragma unroll
      for (int r = 0; r < 4; ++r) {
        lv0[r] = ac0[r] + __shfl_xor(ac0[r], 8) + qbv;
        lv1[r] = ac1[r] + __shfl_xor(ac1[r], 8) + qbv;
        mx0[r] = lv0[r]; mx1[r] = lv1[r];
      }
#pragma unroll
      for (int off = 1; off <= 4; off <<= 1) {
#pragma unroll
        for (int r = 0; r < 4; ++r) {
          mx0[r] = fmaxf(mx0[r], __shfl_xor(mx0[r], off));
          mx1[r] = fmaxf(mx1[r], __shfl_xor(mx1[r], off));
        }
      }
#pragma unroll
      for (int r = 0; r < 4; ++r) {
        a0[r] = __expf(lv0[r] - mx0[r]);
        a1[r] = __expf(lv1[r] - mx1[r]);
        ss0[r] = a0[r]; ss1[r] = a1[r];
      }
#pragma unroll
      for (int off = 1; off <= 4; off <<= 1) {
#pragma unroll
        for (int r = 0; r < 4; ++r) {
          ss0[r] += __shfl_xor(ss0[r], off);
          ss1[r] += __shfl_xor(ss1[r], off);
        }
      }
#pragma unroll
      for (int r = 0; r < 4; ++r) {
        a0[r] *= __frcp_rn(ss0[r]);
        a1[r] *= __frcp_rn(ss1[r]);
      }
    }
    float sacc = 0.0f;
#pragma unroll
    for (int r = 0; r < 4; ++r) sacc += a0[r] + a1[r];
    sacc += __shfl_xor(sacc, 16);
    sacc += __shfl_xor(sacc, 32);
    stot += sacc;

    // ---------------- pack A-fragment: hi planes (lane&8==0) / lo planes ----------------
    bool lop = (lane & 8) != 0;
    V16 au;
    {
      float t8[8];
#pragma unroll
      for (int e = 0; e < 8; ++e) {
        float av = (e < 4) ? a0[e] : a1[e - 4];
        if (lop) {
          __hip_bfloat16 hb = __float2bfloat16(av);
          av = av - __bfloat162float(hb);
        }
        t8[e] = av;
      }
      au.u = make_uint4(pk2bf(t8[0], t8[1]), pk2bf(t8[2], t8[3]),
                        pk2bf(t8[4], t8[5]), pk2bf(t8[6], t8[7]));
    }

    // ---------------- AV: wave w4 owns dc in {4w4..4w4+3}, accumulate ----------------
#pragma unroll
    for (int cc = 0; cc < 4; ++cc) {
      int dc = 4 * w4 + cc;
      int d = dc * 16 + lm, dch = d >> 3, d7b = (d & 7) * 2;
      int r0 = 4 * g, r2 = 16 + 4 * g;
      const char* pl = xwB + (dch << 9) + d7b;
      V16 bu;
      bu.u.x = (uint)*(const ushort*)(pl + ((r0 + 0) << 4)) |
               ((uint)*(const ushort*)(pl + ((r0 + 1) << 4)) << 16);
      bu.u.y = (uint)*(const ushort*)(pl + ((r0 + 2) << 4)) |
               ((uint)*(const ushort*)(pl + ((r0 + 3) << 4)) << 16);
      bu.u.z = (uint)*(const ushort*)(pl + ((r2 + 0) << 4)) |
               ((uint)*(const ushort*)(pl + ((r2 + 1) << 4)) << 16);
      bu.u.w = (uint)*(const ushort*)(pl + ((r2 + 2) << 4)) |
               ((uint)*(const ushort*)(pl + ((r2 + 3) << 4)) << 16);
      avacc[cc] = __builtin_amdgcn_mfma_f32_16x16x32_bf16(au.s, bu.s, avacc[cc], 0, 0, 0);
    }
  }

  // ---------------- epilogue: hi+lo combine, direct uxp store ----------------
  size_t obase = ((size_t)(bI * NCHUNK + c)) * (KK * DD);
#pragma unroll
  for (int cc = 0; cc < 4; ++cc) {
#pragma unroll
    for (int r = 0; r < 4; ++r) {
      float v = avacc[cc][r];
      float o = v + __shfl_xor(v, 32);
      if (lane < 32) uxp[obase + (g * 4 + r) * 256 + (4 * w4 + cc) * 16 + lm] = o;
    }
  }
  if (w4 == 0 && lane < 8) sap[((size_t)(bI * NCHUNK + c)) * KK + lane] = stot;
}

// ---------- Kernel 4: fused slot update, 1 row (b,k) per block, 1024 threads ----------
__global__ __launch_bounds__(1024) void k_fused(const float* __restrict__ slots_in,
                                                const float* __restrict__ uxp,
                                                const float* __restrict__ sap,
                                                const ushort* __restrict__ wb,
                                                const float* __restrict__ bv,
                                                const float* __restrict__ bih, const float* __restrict__ bhh,
                                                const float* __restrict__ gff, const float* __restrict__ bff,
                                                const float* __restrict__ b1, const float* __restrict__ b2,
                                                const float* __restrict__ gs, const float* __restrict__ bs,
                                                const float* __restrict__ bq, const float* __restrict__ bk,
                                                const float* __restrict__ gi, const float* __restrict__ bi,
                                                float* __restrict__ dst,
                                                float* __restrict__ qk_out,
                                                float* __restrict__ qb_out,
                                                int last) {
  const ushort* WG = wb + OFF_G;
  const ushort* W1p = wb + OFF_W1;
  const ushort* W2p = wb + OFF_W2;
  const ushort* WVp = wb + OFF_WV;
  const ushort* WQp = wb + OFF_WQ;
  const ushort* WKp = wb + OFF_WK;

  __shared__ float ux_s[DD], h_s[DD], upd_s[DD], hn_s[DD], ln_s[DD];
  __shared__ float g_s[6][DD];
  __shared__ float hdd_s[HH];
  __shared__ float tmp4_s[4][DD];
  __shared__ float red_s[16];
  __shared__ float sA_s;
  float* tmpH = &tmp4_s[0][0];  // [2][512] alias

  int t = threadIdx.x, d = t & 255, qr = t >> 8;
  int wid = t >> 6, lane = t & 63;
  int r = blockIdx.x, b = r >> 3, k = r & 7;

  // ---- phase 0: reduce 32 attention partials; load h; reduce sA ----
  {
    const float* p = uxp + (((size_t)(b * NCHUNK + qr * 8)) * KK + k) * DD + d;
    float s = 0.0f;
#pragma unroll
    for (int i = 0; i < 8; ++i) s += p[(size_t)i * KK * DD];
    tmp4_s[qr][d] = s;
  }
  if (t < 256) h_s[t] = slots_in[(size_t)r * DD + t];
  if (t >= 960) {
    int c = t - 960;
    float v = (c < NCHUNK) ? sap[((size_t)(b * NCHUNK + c)) * KK + k] : 0.0f;
    v = wave_sum(v);
    if (lane == 0) sA_s = v;
  }
  __syncthreads();
  if (t < 256) ux_s[t] = tmp4_s[0][t] + tmp4_s[1][t] + tmp4_s[2][t] + tmp4_s[3][t];
  __syncthreads();

  // ---- phase 1: upd = WVg.ux + bv'*sA ----
  tmp4_s[qr][d] = gemv_p<256, 64>(WVp, d, qr * 64, ux_s);
  __syncthreads();
  if (t < 256) upd_s[t] = tmp4_s[0][t] + tmp4_s[1][t] + tmp4_s[2][t] + tmp4_s[3][t] + bv[t] * sA_s;
  __syncthreads();

  // ---- phase 2: GRU gates ----
  {
    int g = qr;  // 0..3: ih_r, ih_z, ih_n, hh_r
    const float* src = (g < 3) ? upd_s : h_s;
    float a = gemv_p<256, 256>(WG + (size_t)g * 65536, d, 0, src);
    g_s[g][d] = a + ((g < 3) ? bih[g * 256 + d] : bhh[d]);
    if (t < 512) {
      int g2 = 4 + (t >> 8), j2 = t & 255;  // hh_z, hh_n
      float a2 = gemv_p<256, 256>(WG + (size_t)g2 * 65536, j2, 0, h_s);
      g_s[g2][j2] = a2 + bhh[(g2 - 3) * 256 + j2];
    }
  }
  __syncthreads();
  if (t < 256) {
    float rr = sigmoidf_(g_s[0][t] + g_s[3][t]);
    float zz = sigmoidf_(g_s[1][t] + g_s[4][t]);
    float nn = tanhf(g_s[2][t] + rr * g_s[5][t]);
    hn_s[t] = (1.0f - zz) * nn + zz * h_s[t];
  }
  __syncthreads();

  // ---- phase 3: LN(hn) with ff params ----
  if (t < 256) {
    float v = hn_s[t];
    float sm = wave_sum(v), sq = wave_sum(v * v);
    if (lane == 0) { red_s[wid] = sm; red_s[8 + wid] = sq; }
  }
  __syncthreads();
  if (t < 256) {
    float v = hn_s[t];
    float tot = red_s[0] + red_s[1] + red_s[2] + red_s[3];
    float tot2 = red_s[8] + red_s[9] + red_s[10] + red_s[11];
    float m = tot * (1.0f / DD);
    float var = tot2 * (1.0f / DD) - m * m;
    float rs = rsqrtf(var + LN_EPS);
    ln_s[t] = (v - m) * rs * gff[t] + bff[t];
  }
  __syncthreads();

  // ---- phase 4: hdd = relu(W1.ln + b1) ----
  {
    int o = t & 511, kh = t >> 9;
    tmpH[kh * 512 + o] = gemv_p<512, 128>(W1p, o, kh * 128, ln_s);
  }
  __syncthreads();
  if (t < 512) hdd_s[t] = fmaxf(tmpH[t] + tmpH[512 + t] + b1[t], 0.0f);
  __syncthreads();

  // ---- phase 5: out = hn + W2.hdd + b2 ----
  tmp4_s[qr][d] = gemv_p<256, 128>(W2p, d, qr * 128, hdd_s);
  __syncthreads();
  if (t < 256) {
    float o = hn_s[t] + tmp4_s[0][t] + tmp4_s[1][t] + tmp4_s[2][t] + tmp4_s[3][t] + b2[t];
    dst[(size_t)r * DD + t] = o;
    ux_s[t] = o;  // new slots
  }
  __syncthreads();

  if (!last) {
    // ---- 6a: LN(new slots) with slot params ----
    if (t < 256) {
      float v = ux_s[t];
      float sm = wave_sum(v), sq = wave_sum(v * v);
      if (lane == 0) { red_s[wid] = sm; red_s[8 + wid] = sq; }
    }
    __syncthreads();
    if (t < 256) {
      float v = ux_s[t];
      float tot = red_s[0] + red_s[1] + red_s[2] + red_s[3];
      float tot2 = red_s[8] + red_s[9] + red_s[10] + red_s[11];
      float m = tot * (1.0f / DD);
      float var = tot2 * (1.0f / DD) - m * m;
      float rs = rsqrtf(var + LN_EPS);
      ln_s[t] = (v - m) * rs * gs[t] + bs[t];
    }
    __syncthreads();
    // ---- 6b: q = Wq.ln + bq ----
    tmp4_s[qr][d] = gemv_p<256, 64>(WQp, d, qr * 64, ln_s);
    __syncthreads();
    if (t < 256) {
      float qv = tmp4_s[0][t] + tmp4_s[1][t] + tmp4_s[2][t] + tmp4_s[3][t] + bq[t];
      upd_s[t] = qv;  // q row
      float sb = wave_sum(qv * bk[t]);
      if (lane == 0) red_s[wid] = sb;
    }
    __syncthreads();
    // ---- 6c: qk[j] = SCALE * Wk^T q, with LN-in g/b folded ----
    {
      float a = gemv_p<256, 64>(WKp, d, qr * 64, upd_s);
      tmp4_s[qr][d] = a;
    }
    __syncthreads();
    if (t < 256) {
      float qkv = SCALE * (tmp4_s[0][t] + tmp4_s[1][t] + tmp4_s[2][t] + tmp4_s[3][t]);
      qk_out[(size_t)r * DD + t] = qkv * gi[t];
      float pb2 = wave_sum(qkv * bi[t]);
      if (lane == 0) red_s[8 + wid] = pb2;
    }
    __syncthreads();
    if (t == 0) qb_out[r] = SCALE * (red_s[0] + red_s[1] + red_s[2] + red_s[3]) +
                            red_s[8] + red_s[9] + red_s[10] + red_s[11];
  }
}

extern "C" void kernel_launch(void* const* d_in, const int* in_sizes, int n_in,
                              void* d_out, int out_size, void* d_ws, size_t ws_size,
                              hipStream_t stream) {
  const float* inputs = (const float*)d_in[0];
  const float* slots_init = (const float*)d_in[1];
  const float* ln_in_g = (const float*)d_in[2];
  const float* ln_in_b = (const float*)d_in[3];
  const float* ln_s_g = (const float*)d_in[4];
  const float* ln_s_b = (const float*)d_in[5];
  const float* ln_ff_g = (const float*)d_in[6];
  const float* ln_ff_b = (const float*)d_in[7];
  const float* Wk = (const float*)d_in[8];
  const float* bk = (const float*)d_in[9];
  const float* Wq = (const float*)d_in[10];
  const float* bq = (const float*)d_in[11];
  const float* Wv = (const float*)d_in[12];
  const float* bv = (const float*)d_in[13];
  const float* Wih = (const float*)d_in[14];
  const float* bih = (const float*)d_in[15];
  const float* Whh = (const float*)d_in[16];
  const float* bhh = (const float*)d_in[17];
  const float* W1 = (const float*)d_in[18];
  const float* b1 = (const float*)d_in[19];
  const float* W2 = (const float*)d_in[20];
  const float* b2 = (const float*)d_in[21];
  float* outp = (float*)d_out;

  char* w = (char*)d_ws;
  ushort* xb = (ushort*)w;       w += (size_t)BB * NN * DD * 2;
  float* qk = (float*)w;         w += (size_t)BB * KK * DD * 4;
  float* qb = (float*)w;         w += (size_t)BB * KK * 4;
  float* uxp = (float*)w;        w += (size_t)BB * NCHUNK * KK * DD * 4;
  float* sap = (float*)w;        w += (size_t)BB * NCHUNK * KK * 4;
  float* slots_ws = (float*)w;   w += (size_t)BB * KK * DD * 4;
  ushort* wb = (ushort*)w;       w += (size_t)WB_ELEMS * 2;
  float* bvw = (float*)w;        w += (size_t)DD * 4;

  k_setup<<<G_SETUP, 256, 0, stream>>>(Wih, Whh, W1, W2, Wv, Wq, Wk, wb,
                                       slots_init, ln_s_g, ln_s_b, bq, bk,
                                       ln_in_g, ln_in_b, bv, bvw, qk, qb);

  for (int it = 0; it < 3; ++it) {
    if (it == 0)
      k_attn_t<1><<<BB * 16, 512, 0, stream>>>(nullptr, xb, inputs, qk, qb, uxp, sap);
    else
      k_attn_t<0><<<BB * 16, 512, 0, stream>>>(xb, nullptr, nullptr, qk, qb, uxp, sap);
    const float* sin = (it == 0) ? slots_init : slots_ws;
    float* dst = (it == 2) ? outp : slots_ws;
    k_fused<<<BB * KK, 1024, 0, stream>>>(sin, uxp, sap, wb,
                                          bvw, bih, bhh, ln_ff_g, ln_ff_b, b1, b2,
                                          ln_s_g, ln_s_b, bq, bk, ln_in_g, ln_in_b,
                                          dst, qk, qb, (it == 2) ? 1 : 0);
  }
}

// Round 11
// 240.361 us; speedup vs baseline: 1.1621x; 1.1621x over previous
//
#include <hip/hip_runtime.h>
#include <hip/hip_bf16.h>
#include <cstddef>
#include <cstdint>

#define BB 32
#define NN 4096
#define KK 8
#define DD 256
#define HH 512
#define LN_EPS 1e-5f
#define SCALE 0.0625f  // 1/sqrt(256)
#define NCHUNK 64      // attn partial chunks per batch (2048 blocks, 2 tiles each)

__device__ __forceinline__ float wave_sum(float v) {
#pragma unroll
  for (int off = 32; off >= 1; off >>= 1) v += __shfl_xor(v, off);
  return v;
}

__device__ __forceinline__ float sigmoidf_(float x) { return 1.0f / (1.0f + __expf(-x)); }

__device__ __forceinline__ uint pk2bf(float x, float y) {
  __hip_bfloat16 hx = __float2bfloat16(x), hy = __float2bfloat16(y);
  return (uint)*(ushort*)&hx | ((uint)*(ushort*)&hy << 16);
}

// packed bf16 weight pool offsets (elements).
// layout per matrix (OUT outputs, K inputs): elem(k,j) at (k>>2)*OUT*4 + j*4 + (k&3)
#define OFF_G   0        // 6 gate matrices [ih_r,ih_z,ih_n,hh_r,hh_z,hh_n], 65536 each
#define OFF_W1  393216   // OUT=512 K=256
#define OFF_W2  524288   // OUT=256 K=512
#define OFF_WV  655360   // OUT=256 K=256 (columns pre-scaled by ln_in_g)
#define OFF_WQ  720896   // OUT=256 K=256
#define OFF_WK  786432   // OUT=256(j) K=256(d), src Wk[d*256+j]
#define WB_ELEMS 851968

#define G_PRE (BB * KK)              // 256
#define G_W2B (512 * 11)             // 5632
#define G_SETUP (G_PRE + G_W2B + 1)  // +1 block for bv' = bv + Wv.b

__device__ __forceinline__ float dotp4(uint2 w, float4 s) {
  return __uint_as_float(w.x << 16) * s.x + __uint_as_float(w.x & 0xffff0000u) * s.y +
         __uint_as_float(w.y << 16) * s.z + __uint_as_float(w.y & 0xffff0000u) * s.w;
}

// coalesced packed GEMV partial: output j, k in [kb, kb+KL)
template <int OUT, int KL>
__device__ __forceinline__ float gemv_p(const ushort* __restrict__ wt, int j, int kb,
                                        const float* __restrict__ src) {
  const uint2* p = (const uint2*)(wt + ((size_t)(kb >> 2) * OUT + j) * 4);
  float a = 0.0f;
#pragma unroll 16
  for (int e = 0; e < KL / 4; ++e) {
    uint2 w = p[(size_t)e * OUT];
    float4 s = *(const float4*)(src + kb + e * 4);
    a += dotp4(w, s);
  }
  return a;
}

// ---------- Kernel 1 (setup): slots_pre + w2b pack + bv' ----------
__global__ __launch_bounds__(256) void k_setup(
    const float* __restrict__ Wih, const float* __restrict__ Whh,
    const float* __restrict__ W1, const float* __restrict__ W2,
    const float* __restrict__ Wv, const float* __restrict__ Wq,
    const float* __restrict__ Wk, ushort* __restrict__ wb,
    const float* __restrict__ slots, const float* __restrict__ gs, const float* __restrict__ bs,
    const float* __restrict__ bq, const float* __restrict__ bk,
    const float* __restrict__ gi, const float* __restrict__ bi,
    const float* __restrict__ bv, float* __restrict__ bvw,
    float* __restrict__ qk, float* __restrict__ qb) {
  int blk = blockIdx.x;
  if (blk < G_PRE) {
    // ---- initial qk/qb from slots_init (fp32 weights), with g/b folded ----
    int row = blk;
    int t = threadIdx.x;
    int wid = t >> 6, lane = t & 63;
    __shared__ float lns[DD];
    __shared__ float qs[DD];
    __shared__ float rb[8];
    float sv = slots[(size_t)row * DD + t];
    float s = wave_sum(sv);
    float s2 = wave_sum(sv * sv);
    if (lane == 0) { rb[wid] = s; rb[4 + wid] = s2; }
    __syncthreads();
    float tot = rb[0] + rb[1] + rb[2] + rb[3];
    float tot2 = rb[4] + rb[5] + rb[6] + rb[7];
    float m = tot * (1.0f / DD);
    float var = tot2 * (1.0f / DD) - m * m;
    float rs = rsqrtf(var + LN_EPS);
    lns[t] = (sv - m) * rs * gs[t] + bs[t];
    __syncthreads();
    float acc = 0.0f;
    const float4* wr = (const float4*)(Wq + (size_t)t * DD);
#pragma unroll 4
    for (int e4 = 0; e4 < DD / 4; ++e4) {
      float4 w = wr[e4];
      float4 l = ((const float4*)lns)[e4];
      acc += w.x * l.x + w.y * l.y + w.z * l.z + w.w * l.w;
    }
    qs[t] = acc + bq[t];
    __syncthreads();
    float a2 = 0.0f;
    for (int d = 0; d < DD; ++d) a2 = fmaf(qs[d], Wk[(size_t)d * DD + t], a2);
    float a2S = SCALE * a2;
    qk[(size_t)row * DD + t] = a2S * gi[t];
    float pb = wave_sum(qs[t] * bk[t]);
    float pb2 = wave_sum(a2S * bi[t]);
    __syncthreads();
    if (lane == 0) { rb[wid] = pb; rb[4 + wid] = pb2; }
    __syncthreads();
    if (t == 0) qb[row] = SCALE * (rb[0] + rb[1] + rb[2] + rb[3]) + rb[4] + rb[5] + rb[6] + rb[7];
  } else if (blk < G_PRE + G_W2B) {
    // ---- pack weights to bf16 ----
    int q2 = blk - G_PRE;
    int m = q2 >> 9;             // /512
    int idx = (q2 & 511) * 256 + threadIdx.x;
    const int sizes[11] = {65536, 65536, 65536, 65536, 65536, 65536, 131072, 131072, 65536, 65536, 65536};
    const int offs[11] = {OFF_G, OFF_G + 65536, OFF_G + 131072, OFF_G + 196608, OFF_G + 262144,
                          OFF_G + 327680, OFF_W1, OFF_W2, OFF_WV, OFF_WQ, OFF_WK};
    if (idx >= sizes[m]) return;
    int K = (m == 7) ? 512 : 256;
    int OUT = (m == 6) ? 512 : 256;
    int k = idx % K, j = idx / K;
    float v;
    switch (m) {
      case 0: case 1: case 2: v = Wih[((size_t)(m * 256 + j)) * 256 + k]; break;
      case 3: case 4: case 5: v = Whh[((size_t)((m - 3) * 256 + j)) * 256 + k]; break;
      case 6: v = W1[(size_t)j * 256 + k]; break;
      case 7: v = W2[(size_t)j * 512 + k]; break;
      case 8: v = Wv[(size_t)j * 256 + k] * gi[k]; break;  // fold LN gamma
      case 9: v = Wq[(size_t)j * 256 + k]; break;
      default: v = Wk[(size_t)k * 256 + j]; break;
    }
    __hip_bfloat16 h = __float2bfloat16(v);
    wb[(size_t)offs[m] + (size_t)(k >> 2) * OUT * 4 + j * 4 + (k & 3)] = *(ushort*)&h;
  } else {
    // ---- bv' = bv + Wv . ln_in_b ----
    int t = threadIdx.x;
    float a = bv[t];
    const float4* wr = (const float4*)(Wv + (size_t)t * DD);
    const float4* bb = (const float4*)bi;
#pragma unroll 4
    for (int e4 = 0; e4 < DD / 4; ++e4) {
      float4 w = wr[e4];
      float4 x = bb[e4];
      a += w.x * x.x + w.y * x.y + w.z * x.z + w.w * x.w;
    }
    bvw[t] = a;
  }
}

// ---------- Kernel 3: MFMA attention, 256-thread blocks, 24KB LDS ----------
// Per block: 2 tiles of 32 rows (chunk c = 64 rows); ONE 16KB tile buffer,
// plane layout byte(row,d) = (d>>3)*512 + row*16 + (d&7)*2 (xb image == LDS).
// Per tile: [barrier] -> 4x global_load_lds per wave -> vmcnt drain+barrier
// -> full QK (16 MFMA, redundant per wave) -> lane-local softmax -> AV (wave
// owns dc quarter, accumulators persist across tiles). LDS = 8(q_l)+16 = 24KB
// -> 6 blocks/CU (24 waves) when VGPR<=64. Math identical to R8/R9-verified.
template <int DO_LN>
__global__ __launch_bounds__(256, 4) void k_attn_t(const ushort* __restrict__ xb_in,
                                                   ushort* __restrict__ xb_out,
                                                   const float* __restrict__ inp,
                                                   const float* __restrict__ qk,
                                                   const float* __restrict__ qb,
                                                   float* __restrict__ uxp,
                                                   float* __restrict__ sap) {
  typedef __attribute__((ext_vector_type(8))) short short8;
  typedef __attribute__((ext_vector_type(4))) float f32x4;
  union V16 { uint4 u; short8 s; ushort us[8]; };

  __shared__ __align__(16) ushort q_l[16 * 256];   // 8KB: qh slot-rows 0-7, ql 8-15
  __shared__ __align__(16) ushort xtile[32 * 256]; // 16KB tile buffer

  int t = threadIdx.x, wid = t >> 6, lane = t & 63;
  int bI = blockIdx.x >> 6, c = blockIdx.x & 63;
  int lm = lane & 15, g = lane >> 4;
  char* qB = (char*)q_l;
  ushort* xw = xtile;
  char* xwB = (char*)xw;

  // ---- stage q hi/lo planes into rotated plane layout (R7-proven) ----
  {
    const float* qkb = qk + (size_t)bI * (KK * DD);
    int p = t >> 3, e7 = t & 7;
#pragma unroll 1
    for (int s = 0; s < 8; ++s) {
      float qv = qkb[s * 256 + t];
      __hip_bfloat16 hb = __float2bfloat16(qv);
      float lo = qv - __bfloat162float(hb);
      __hip_bfloat16 lb = __float2bfloat16(lo);
      *(ushort*)(qB + s * 512 + (((p + s) & 31) << 4) + e7 * 2) = *(ushort*)&hb;
      *(ushort*)(qB + (s + 8) * 512 + (((p + s + 8) & 31) << 4) + e7 * 2) = *(ushort*)&lb;
    }
  }
  float qbv = qb[bI * 8 + (lane & 7)];

  f32x4 avacc[4];
#pragma unroll
  for (int i = 0; i < 4; ++i) avacc[i] = (f32x4){0.0f, 0.0f, 0.0f, 0.0f};
  float stot = 0.0f;

#pragma unroll 1
  for (int tt = 0; tt < 2; ++tt) {
    int row0 = c * 64 + tt * 32;

    if (DO_LN) {
      __syncthreads();  // buffer reuse (tt=1) / q_l ready (tt=0)
      int q8 = t & 7, rr = t >> 3;
      const float* rp = inp + ((size_t)bI * NN + row0 + rr) * DD + q8 * 4;
      float4 cur[8];
#pragma unroll
      for (int i = 0; i < 8; ++i) cur[i] = *(const float4*)(rp + i * 32);
      float s1 = 0.0f, s2 = 0.0f;
#pragma unroll
      for (int i = 0; i < 8; ++i) {
        s1 += cur[i].x + cur[i].y + cur[i].z + cur[i].w;
        s2 += cur[i].x * cur[i].x + cur[i].y * cur[i].y + cur[i].z * cur[i].z + cur[i].w * cur[i].w;
      }
      s1 += __shfl_xor(s1, 1); s2 += __shfl_xor(s2, 1);
      s1 += __shfl_xor(s1, 2); s2 += __shfl_xor(s2, 2);
      s1 += __shfl_xor(s1, 4); s2 += __shfl_xor(s2, 4);
      float m = s1 * (1.0f / DD);
      float var = s2 * (1.0f / DD) - m * m;
      float rs = rsqrtf(var + LN_EPS);
      int pb = q8 >> 1, hb8 = (q8 & 1) * 8;
#pragma unroll
      for (int i = 0; i < 8; ++i) {
        uint2 wv;
        wv.x = pk2bf((cur[i].x - m) * rs, (cur[i].y - m) * rs);
        wv.y = pk2bf((cur[i].z - m) * rs, (cur[i].w - m) * rs);
        *(uint2*)(xwB + ((4 * i + pb) << 9) + (rr << 4) + hb8) = wv;
      }
      __syncthreads();  // tile image complete
      ushort* xbt = xb_out + ((size_t)bI * NN + row0) * DD;
#pragma unroll
      for (int i = 0; i < 4; ++i)
        *(uint4*)((char*)xbt + i * 4096 + t * 16) = *(const uint4*)(xwB + i * 4096 + t * 16);
    } else {
      if (tt) __syncthreads();  // prev tile consumed by all waves
      const ushort* srcb = xb_in + ((size_t)bI * NN + row0) * DD;
#pragma unroll
      for (int i = 0; i < 4; ++i) {
        __builtin_amdgcn_global_load_lds(
            (__attribute__((address_space(1))) void*)(srcb + i * 2048 + wid * 512 + lane * 8),
            (__attribute__((address_space(3))) void*)(xw + i * 2048 + wid * 512), 16, 0, 0);
      }
      asm volatile("s_waitcnt vmcnt(0) lgkmcnt(0)" ::: "memory");
      __builtin_amdgcn_sched_barrier(0);
      __syncthreads();  // all waves' loads landed; q_l ready (tt=0)
    }

    // ---------------- QK full (16 MFMAs, redundant per wave) ----------------
    int rA = lm, rB = lm + 16;
    f32x4 ac0 = {}, ac1 = {};
#pragma unroll
    for (int kk = 0; kk < 8; ++kk) {
      V16 qf, x0, x1;
      int ch = kk * 4 + g;
      qf.u = *(const uint4*)(qB + (lm << 9) + (((ch + lm) & 31) << 4));
      x0.u = *(const uint4*)(xwB + (ch << 9) + (rA << 4));
      x1.u = *(const uint4*)(xwB + (ch << 9) + (rB << 4));
      ac0 = __builtin_amdgcn_mfma_f32_16x16x32_bf16(x0.s, qf.s, ac0, 0, 0, 0);
      ac1 = __builtin_amdgcn_mfma_f32_16x16x32_bf16(x1.s, qf.s, ac1, 0, 0, 0);
    }

    // ---------------- softmax over slots (lane octet), rows vectorized ----------------
    float a0[4], a1[4];
    {
      float lv0[4], lv1[4], mx0[4], mx1[4], ss0[4], ss1[4];
#pragma unroll
      for (int r = 0; r < 4; ++r) {
        lv0[r] = ac0[r] + __shfl_xor(ac0[r], 8) + qbv;
        lv1[r] = ac1[r] + __shfl_xor(ac1[r], 8) + qbv;
        mx0[r] = lv0[r]; mx1[r] = lv1[r];
      }
#pragma unroll
      for (int off = 1; off <= 4; off <<= 1) {
#pragma unroll
        for (int r = 0; r < 4; ++r) {
          mx0[r] = fmaxf(mx0[r], __shfl_xor(mx0[r], off));
          mx1[r] = fmaxf(mx1[r], __shfl_xor(mx1[r], off));
        }
      }
#pragma unroll
      for (int r = 0; r < 4; ++r) {
        a0[r] = __expf(lv0[r] - mx0[r]);
        a1[r] = __expf(lv1[r] - mx1[r]);
        ss0[r] = a0[r]; ss1[r] = a1[r];
      }
#pragma unroll
      for (int off = 1; off <= 4; off <<= 1) {
#pragma unroll
        for (int r = 0; r < 4; ++r) {
          ss0[r] += __shfl_xor(ss0[r], off);
          ss1[r] += __shfl_xor(ss1[r], off);
        }
      }
#pragma unroll
      for (int r = 0; r < 4; ++r) {
        a0[r] *= __frcp_rn(ss0[r]);
        a1[r] *= __frcp_rn(ss1[r]);
      }
    }
    float sacc = 0.0f;
#pragma unroll
    for (int r = 0; r < 4; ++r) sacc += a0[r] + a1[r];
    sacc += __shfl_xor(sacc, 16);
    sacc += __shfl_xor(sacc, 32);
    stot += sacc;

    // ---------------- pack A-fragment: hi planes (lane&8==0) / lo planes ----------------
    bool lop = (lane & 8) != 0;
    V16 au;
    {
      float t8[8];
#pragma unroll
      for (int e = 0; e < 8; ++e) {
        float av = (e < 4) ? a0[e] : a1[e - 4];
        if (lop) {
          __hip_bfloat16 hb = __float2bfloat16(av);
          av = av - __bfloat162float(hb);
        }
        t8[e] = av;
      }
      au.u = make_uint4(pk2bf(t8[0], t8[1]), pk2bf(t8[2], t8[3]),
                        pk2bf(t8[4], t8[5]), pk2bf(t8[6], t8[7]));
    }

    // ---------------- AV: wave wid owns dc in {4wid..4wid+3}, accumulate ----------------
#pragma unroll
    for (int cc = 0; cc < 4; ++cc) {
      int dc = 4 * wid + cc;
      int d = dc * 16 + lm, dch = d >> 3, d7b = (d & 7) * 2;
      int r0 = 4 * g, r2 = 16 + 4 * g;
      const char* pl = xwB + (dch << 9) + d7b;
      V16 bu;
      bu.u.x = (uint)*(const ushort*)(pl + ((r0 + 0) << 4)) |
               ((uint)*(const ushort*)(pl + ((r0 + 1) << 4)) << 16);
      bu.u.y = (uint)*(const ushort*)(pl + ((r0 + 2) << 4)) |
               ((uint)*(const ushort*)(pl + ((r0 + 3) << 4)) << 16);
      bu.u.z = (uint)*(const ushort*)(pl + ((r2 + 0) << 4)) |
               ((uint)*(const ushort*)(pl + ((r2 + 1) << 4)) << 16);
      bu.u.w = (uint)*(const ushort*)(pl + ((r2 + 2) << 4)) |
               ((uint)*(const ushort*)(pl + ((r2 + 3) << 4)) << 16);
      avacc[cc] = __builtin_amdgcn_mfma_f32_16x16x32_bf16(au.s, bu.s, avacc[cc], 0, 0, 0);
    }
  }

  // ---------------- epilogue: hi+lo combine, direct uxp store ----------------
  size_t obase = ((size_t)(bI * NCHUNK + c)) * (KK * DD);
#pragma unroll
  for (int cc = 0; cc < 4; ++cc) {
#pragma unroll
    for (int r = 0; r < 4; ++r) {
      float v = avacc[cc][r];
      float o = v + __shfl_xor(v, 32);
      if (lane < 32) uxp[obase + (g * 4 + r) * 256 + (4 * wid + cc) * 16 + lm] = o;
    }
  }
  if (wid == 0 && lane < 8) sap[((size_t)(bI * NCHUNK + c)) * KK + lane] = stot;
}

// ---------- Kernel 4: fused slot update, 1 row (b,k) per block, 1024 threads ----------
__global__ __launch_bounds__(1024) void k_fused(const float* __restrict__ slots_in,
                                                const float* __restrict__ uxp,
                                                const float* __restrict__ sap,
                                                const ushort* __restrict__ wb,
                                                const float* __restrict__ bv,
                                                const float* __restrict__ bih, const float* __restrict__ bhh,
                                                const float* __restrict__ gff, const float* __restrict__ bff,
                                                const float* __restrict__ b1, const float* __restrict__ b2,
                                                const float* __restrict__ gs, const float* __restrict__ bs,
                                                const float* __restrict__ bq, const float* __restrict__ bk,
                                                const float* __restrict__ gi, const float* __restrict__ bi,
                                                float* __restrict__ dst,
                                                float* __restrict__ qk_out,
                                                float* __restrict__ qb_out,
                                                int last) {
  const ushort* WG = wb + OFF_G;
  const ushort* W1p = wb + OFF_W1;
  const ushort* W2p = wb + OFF_W2;
  const ushort* WVp = wb + OFF_WV;
  const ushort* WQp = wb + OFF_WQ;
  const ushort* WKp = wb + OFF_WK;

  __shared__ float ux_s[DD], h_s[DD], upd_s[DD], hn_s[DD], ln_s[DD];
  __shared__ float g_s[6][DD];
  __shared__ float hdd_s[HH];
  __shared__ float tmp4_s[4][DD];
  __shared__ float red_s[16];
  __shared__ float sA_s;
  float* tmpH = &tmp4_s[0][0];  // [2][512] alias

  int t = threadIdx.x, d = t & 255, qr = t >> 8;
  int wid = t >> 6, lane = t & 63;
  int r = blockIdx.x, b = r >> 3, k = r & 7;

  // ---- phase 0: reduce 64 attention partials; load h; reduce sA ----
  {
    const float* p = uxp + (((size_t)(b * NCHUNK + qr * 16)) * KK + k) * DD + d;
    float s = 0.0f;
#pragma unroll
    for (int i = 0; i < 16; ++i) s += p[(size_t)i * KK * DD];
    tmp4_s[qr][d] = s;
  }
  if (t < 256) h_s[t] = slots_in[(size_t)r * DD + t];
  if (t >= 960) {
    int c = t - 960;
    float v = (c < NCHUNK) ? sap[((size_t)(b * NCHUNK + c)) * KK + k] : 0.0f;
    v = wave_sum(v);
    if (lane == 0) sA_s = v;
  }
  __syncthreads();
  if (t < 256) ux_s[t] = tmp4_s[0][t] + tmp4_s[1][t] + tmp4_s[2][t] + tmp4_s[3][t];
  __syncthreads();

  // ---- phase 1: upd = WVg.ux + bv'*sA ----
  tmp4_s[qr][d] = gemv_p<256, 64>(WVp, d, qr * 64, ux_s);
  __syncthreads();
  if (t < 256) upd_s[t] = tmp4_s[0][t] + tmp4_s[1][t] + tmp4_s[2][t] + tmp4_s[3][t] + bv[t] * sA_s;
  __syncthreads();

  // ---- phase 2: GRU gates ----
  {
    int g = qr;  // 0..3: ih_r, ih_z, ih_n, hh_r
    const float* src = (g < 3) ? upd_s : h_s;
    float a = gemv_p<256, 256>(WG + (size_t)g * 65536, d, 0, src);
    g_s[g][d] = a + ((g < 3) ? bih[g * 256 + d] : bhh[d]);
    if (t < 512) {
      int g2 = 4 + (t >> 8), j2 = t & 255;  // hh_z, hh_n
      float a2 = gemv_p<256, 256>(WG + (size_t)g2 * 65536, j2, 0, h_s);
      g_s[g2][j2] = a2 + bhh[(g2 - 3) * 256 + j2];
    }
  }
  __syncthreads();
  if (t < 256) {
    float rr = sigmoidf_(g_s[0][t] + g_s[3][t]);
    float zz = sigmoidf_(g_s[1][t] + g_s[4][t]);
    float nn = tanhf(g_s[2][t] + rr * g_s[5][t]);
    hn_s[t] = (1.0f - zz) * nn + zz * h_s[t];
  }
  __syncthreads();

  // ---- phase 3: LN(hn) with ff params ----
  if (t < 256) {
    float v = hn_s[t];
    float sm = wave_sum(v), sq = wave_sum(v * v);
    if (lane == 0) { red_s[wid] = sm; red_s[8 + wid] = sq; }
  }
  __syncthreads();
  if (t < 256) {
    float v = hn_s[t];
    float tot = red_s[0] + red_s[1] + red_s[2] + red_s[3];
    float tot2 = red_s[8] + red_s[9] + red_s[10] + red_s[11];
    float m = tot * (1.0f / DD);
    float var = tot2 * (1.0f / DD) - m * m;
    float rs = rsqrtf(var + LN_EPS);
    ln_s[t] = (v - m) * rs * gff[t] + bff[t];
  }
  __syncthreads();

  // ---- phase 4: hdd = relu(W1.ln + b1) ----
  {
    int o = t & 511, kh = t >> 9;
    tmpH[kh * 512 + o] = gemv_p<512, 128>(W1p, o, kh * 128, ln_s);
  }
  __syncthreads();
  if (t < 512) hdd_s[t] = fmaxf(tmpH[t] + tmpH[512 + t] + b1[t], 0.0f);
  __syncthreads();

  // ---- phase 5: out = hn + W2.hdd + b2 ----
  tmp4_s[qr][d] = gemv_p<256, 128>(W2p, d, qr * 128, hdd_s);
  __syncthreads();
  if (t < 256) {
    float o = hn_s[t] + tmp4_s[0][t] + tmp4_s[1][t] + tmp4_s[2][t] + tmp4_s[3][t] + b2[t];
    dst[(size_t)r * DD + t] = o;
    ux_s[t] = o;  // new slots
  }
  __syncthreads();

  if (!last) {
    // ---- 6a: LN(new slots) with slot params ----
    if (t < 256) {
      float v = ux_s[t];
      float sm = wave_sum(v), sq = wave_sum(v * v);
      if (lane == 0) { red_s[wid] = sm; red_s[8 + wid] = sq; }
    }
    __syncthreads();
    if (t < 256) {
      float v = ux_s[t];
      float tot = red_s[0] + red_s[1] + red_s[2] + red_s[3];
      float tot2 = red_s[8] + red_s[9] + red_s[10] + red_s[11];
      float m = tot * (1.0f / DD);
      float var = tot2 * (1.0f / DD) - m * m;
      float rs = rsqrtf(var + LN_EPS);
      ln_s[t] = (v - m) * rs * gs[t] + bs[t];
    }
    __syncthreads();
    // ---- 6b: q = Wq.ln + bq ----
    tmp4_s[qr][d] = gemv_p<256, 64>(WQp, d, qr * 64, ln_s);
    __syncthreads();
    if (t < 256) {
      float qv = tmp4_s[0][t] + tmp4_s[1][t] + tmp4_s[2][t] + tmp4_s[3][t] + bq[t];
      upd_s[t] = qv;  // q row
      float sb = wave_sum(qv * bk[t]);
      if (lane == 0) red_s[wid] = sb;
    }
    __syncthreads();
    // ---- 6c: qk[j] = SCALE * Wk^T q, with LN-in g/b folded ----
    {
      float a = gemv_p<256, 64>(WKp, d, qr * 64, upd_s);
      tmp4_s[qr][d] = a;
    }
    __syncthreads();
    if (t < 256) {
      float qkv = SCALE * (tmp4_s[0][t] + tmp4_s[1][t] + tmp4_s[2][t] + tmp4_s[3][t]);
      qk_out[(size_t)r * DD + t] = qkv * gi[t];
      float pb2 = wave_sum(qkv * bi[t]);
      if (lane == 0) red_s[8 + wid] = pb2;
    }
    __syncthreads();
    if (t == 0) qb_out[r] = SCALE * (red_s[0] + red_s[1] + red_s[2] + red_s[3]) +
                            red_s[8] + red_s[9] + red_s[10] + red_s[11];
  }
}

extern "C" void kernel_launch(void* const* d_in, const int* in_sizes, int n_in,
                              void* d_out, int out_size, void* d_ws, size_t ws_size,
                              hipStream_t stream) {
  const float* inputs = (const float*)d_in[0];
  const float* slots_init = (const float*)d_in[1];
  const float* ln_in_g = (const float*)d_in[2];
  const float* ln_in_b = (const float*)d_in[3];
  const float* ln_s_g = (const float*)d_in[4];
  const float* ln_s_b = (const float*)d_in[5];
  const float* ln_ff_g = (const float*)d_in[6];
  const float* ln_ff_b = (const float*)d_in[7];
  const float* Wk = (const float*)d_in[8];
  const float* bk = (const float*)d_in[9];
  const float* Wq = (const float*)d_in[10];
  const float* bq = (const float*)d_in[11];
  const float* Wv = (const float*)d_in[12];
  const float* bv = (const float*)d_in[13];
  const float* Wih = (const float*)d_in[14];
  const float* bih = (const float*)d_in[15];
  const float* Whh = (const float*)d_in[16];
  const float* bhh = (const float*)d_in[17];
  const float* W1 = (const float*)d_in[18];
  const float* b1 = (const float*)d_in[19];
  const float* W2 = (const float*)d_in[20];
  const float* b2 = (const float*)d_in[21];
  float* outp = (float*)d_out;

  char* w = (char*)d_ws;
  ushort* xb = (ushort*)w;       w += (size_t)BB * NN * DD * 2;
  float* qk = (float*)w;         w += (size_t)BB * KK * DD * 4;
  float* qb = (float*)w;         w += (size_t)BB * KK * 4;
  float* uxp = (float*)w;        w += (size_t)BB * NCHUNK * KK * DD * 4;
  float* sap = (float*)w;        w += (size_t)BB * NCHUNK * KK * 4;
  float* slots_ws = (float*)w;   w += (size_t)BB * KK * DD * 4;
  ushort* wb = (ushort*)w;       w += (size_t)WB_ELEMS * 2;
  float* bvw = (float*)w;        w += (size_t)DD * 4;

  k_setup<<<G_SETUP, 256, 0, stream>>>(Wih, Whh, W1, W2, Wv, Wq, Wk, wb,
                                       slots_init, ln_s_g, ln_s_b, bq, bk,
                                       ln_in_g, ln_in_b, bv, bvw, qk, qb);

  for (int it = 0; it < 3; ++it) {
    if (it == 0)
      k_attn_t<1><<<BB * NCHUNK, 256, 0, stream>>>(nullptr, xb, inputs, qk, qb, uxp, sap);
    else
      k_attn_t<0><<<BB * NCHUNK, 256, 0, stream>>>(xb, nullptr, nullptr, qk, qb, uxp, sap);
    const float* sin = (it == 0) ? slots_init : slots_ws;
    float* dst = (it == 2) ? outp : slots_ws;
    k_fused<<<BB * KK, 1024, 0, stream>>>(sin, uxp, sap, wb,
                                          bvw, bih, bhh, ln_ff_g, ln_ff_b, b1, b2,
                                          ln_s_g, ln_s_b, bq, bk, ln_in_g, ln_in_b,
                                          dst, qk, qb, (it == 2) ? 1 : 0);
  }
}

// Round 12
// 230.609 us; speedup vs baseline: 1.2112x; 1.0423x over previous
//
#include <hip/hip_runtime.h>
#include <hip/hip_bf16.h>
#include <cstddef>
#include <cstdint>

#define BB 32
#define NN 4096
#define KK 8
#define DD 256
#define HH 512
#define LN_EPS 1e-5f
#define SCALE 0.0625f  // 1/sqrt(256)
#define NCHUNK 32      // attn partial chunks per batch (1024 blocks)

__device__ __forceinline__ float wave_sum(float v) {
#pragma unroll
  for (int off = 32; off >= 1; off >>= 1) v += __shfl_xor(v, off);
  return v;
}

__device__ __forceinline__ float sigmoidf_(float x) { return 1.0f / (1.0f + __expf(-x)); }

__device__ __forceinline__ uint pk2bf(float x, float y) {
  __hip_bfloat16 hx = __float2bfloat16(x), hy = __float2bfloat16(y);
  return (uint)*(ushort*)&hx | ((uint)*(ushort*)&hy << 16);
}

// packed bf16 weight pool offsets (elements).
// layout per matrix (OUT outputs, K inputs): elem(k,j) at (k>>2)*OUT*4 + j*4 + (k&3)
#define OFF_G   0        // 6 gate matrices [ih_r,ih_z,ih_n,hh_r,hh_z,hh_n], 65536 each
#define OFF_W1  393216   // OUT=512 K=256
#define OFF_W2  524288   // OUT=256 K=512
#define OFF_WV  655360   // OUT=256 K=256 (columns pre-scaled by ln_in_g)
#define OFF_WQ  720896   // OUT=256 K=256
#define OFF_WK  786432   // OUT=256(j) K=256(d), src Wk[d*256+j]
#define WB_ELEMS 851968

#define G_PRE (BB * KK)              // 256
#define G_W2B (512 * 11)             // 5632
#define G_SETUP (G_PRE + G_W2B + 1)  // +1 block for bv' = bv + Wv.b

__device__ __forceinline__ float dotp4(uint2 w, float4 s) {
  return __uint_as_float(w.x << 16) * s.x + __uint_as_float(w.x & 0xffff0000u) * s.y +
         __uint_as_float(w.y << 16) * s.z + __uint_as_float(w.y & 0xffff0000u) * s.w;
}

// coalesced packed GEMV partial: output j, k in [kb, kb+KL)
template <int OUT, int KL>
__device__ __forceinline__ float gemv_p(const ushort* __restrict__ wt, int j, int kb,
                                        const float* __restrict__ src) {
  const uint2* p = (const uint2*)(wt + ((size_t)(kb >> 2) * OUT + j) * 4);
  float a = 0.0f;
#pragma unroll 16
  for (int e = 0; e < KL / 4; ++e) {
    uint2 w = p[(size_t)e * OUT];
    float4 s = *(const float4*)(src + kb + e * 4);
    a += dotp4(w, s);
  }
  return a;
}

// ---------- Kernel 1 (setup): slots_pre + w2b pack + bv' ----------
__global__ __launch_bounds__(256) void k_setup(
    const float* __restrict__ Wih, const float* __restrict__ Whh,
    const float* __restrict__ W1, const float* __restrict__ W2,
    const float* __restrict__ Wv, const float* __restrict__ Wq,
    const float* __restrict__ Wk, ushort* __restrict__ wb,
    const float* __restrict__ slots, const float* __restrict__ gs, const float* __restrict__ bs,
    const float* __restrict__ bq, const float* __restrict__ bk,
    const float* __restrict__ gi, const float* __restrict__ bi,
    const float* __restrict__ bv, float* __restrict__ bvw,
    float* __restrict__ qk, float* __restrict__ qb) {
  int blk = blockIdx.x;
  if (blk < G_PRE) {
    // ---- initial qk/qb from slots_init (fp32 weights), with g/b folded ----
    int row = blk;
    int t = threadIdx.x;
    int wid = t >> 6, lane = t & 63;
    __shared__ float lns[DD];
    __shared__ float qs[DD];
    __shared__ float rb[8];
    float sv = slots[(size_t)row * DD + t];
    float s = wave_sum(sv);
    float s2 = wave_sum(sv * sv);
    if (lane == 0) { rb[wid] = s; rb[4 + wid] = s2; }
    __syncthreads();
    float tot = rb[0] + rb[1] + rb[2] + rb[3];
    float tot2 = rb[4] + rb[5] + rb[6] + rb[7];
    float m = tot * (1.0f / DD);
    float var = tot2 * (1.0f / DD) - m * m;
    float rs = rsqrtf(var + LN_EPS);
    lns[t] = (sv - m) * rs * gs[t] + bs[t];
    __syncthreads();
    float acc = 0.0f;
    const float4* wr = (const float4*)(Wq + (size_t)t * DD);
#pragma unroll 4
    for (int e4 = 0; e4 < DD / 4; ++e4) {
      float4 w = wr[e4];
      float4 l = ((const float4*)lns)[e4];
      acc += w.x * l.x + w.y * l.y + w.z * l.z + w.w * l.w;
    }
    qs[t] = acc + bq[t];
    __syncthreads();
    float a2 = 0.0f;
    for (int d = 0; d < DD; ++d) a2 = fmaf(qs[d], Wk[(size_t)d * DD + t], a2);
    float a2S = SCALE * a2;
    qk[(size_t)row * DD + t] = a2S * gi[t];
    float pb = wave_sum(qs[t] * bk[t]);
    float pb2 = wave_sum(a2S * bi[t]);
    __syncthreads();
    if (lane == 0) { rb[wid] = pb; rb[4 + wid] = pb2; }
    __syncthreads();
    if (t == 0) qb[row] = SCALE * (rb[0] + rb[1] + rb[2] + rb[3]) + rb[4] + rb[5] + rb[6] + rb[7];
  } else if (blk < G_PRE + G_W2B) {
    // ---- pack weights to bf16 ----
    int q2 = blk - G_PRE;
    int m = q2 >> 9;             // /512
    int idx = (q2 & 511) * 256 + threadIdx.x;
    const int sizes[11] = {65536, 65536, 65536, 65536, 65536, 65536, 131072, 131072, 65536, 65536, 65536};
    const int offs[11] = {OFF_G, OFF_G + 65536, OFF_G + 131072, OFF_G + 196608, OFF_G + 262144,
                          OFF_G + 327680, OFF_W1, OFF_W2, OFF_WV, OFF_WQ, OFF_WK};
    if (idx >= sizes[m]) return;
    int K = (m == 7) ? 512 : 256;
    int OUT = (m == 6) ? 512 : 256;
    int k = idx % K, j = idx / K;
    float v;
    switch (m) {
      case 0: case 1: case 2: v = Wih[((size_t)(m * 256 + j)) * 256 + k]; break;
      case 3: case 4: case 5: v = Whh[((size_t)((m - 3) * 256 + j)) * 256 + k]; break;
      case 6: v = W1[(size_t)j * 256 + k]; break;
      case 7: v = W2[(size_t)j * 512 + k]; break;
      case 8: v = Wv[(size_t)j * 256 + k] * gi[k]; break;  // fold LN gamma
      case 9: v = Wq[(size_t)j * 256 + k]; break;
      default: v = Wk[(size_t)k * 256 + j]; break;
    }
    __hip_bfloat16 h = __float2bfloat16(v);
    wb[(size_t)offs[m] + (size_t)(k >> 2) * OUT * 4 + j * 4 + (k & 3)] = *(ushort*)&h;
  } else {
    // ---- bv' = bv + Wv . ln_in_b ----
    int t = threadIdx.x;
    float a = bv[t];
    const float4* wr = (const float4*)(Wv + (size_t)t * DD);
    const float4* bb = (const float4*)bi;
#pragma unroll 4
    for (int e4 = 0; e4 < DD / 4; ++e4) {
      float4 w = wr[e4];
      float4 x = bb[e4];
      a += w.x * x.x + w.y * x.y + w.z * x.z + w.w * x.w;
    }
    bvw[t] = a;
  }
}

// ---------- Kernel 3: MFMA attention, 4-wave cooperative K-split ----------
// Per block: ONE shared 32-row tile at a time (4 tiles sequentially), plane
// layout byte(row,d) = (d>>3)*512 + row*16 + (d&7)*2  (xb global image ==
// LDS image).  Per tile:
//   QK: wave w computes k-steps kk in {2w,2w+1} (4 MFMAs) -> partial D to
//       scr[w]; barrier; every wave sums the 4 partials (identical result)
//       and runs the R7-proven softmax redundantly.
//   AV: wave w owns dc in {4w..4w+3}; accumulators persist in registers
//       across tiles (rows sum); no LDS block-combine needed.
// LDS = 8(q) + 16(tile) + 8(scratch) = 32KB; session-best config (230.9us).
template <int DO_LN>
__global__ __launch_bounds__(256, 4) void k_attn_t(const ushort* __restrict__ xb_in,
                                                   ushort* __restrict__ xb_out,
                                                   const float* __restrict__ inp,
                                                   const float* __restrict__ qk,
                                                   const float* __restrict__ qb,
                                                   float* __restrict__ uxp,
                                                   float* __restrict__ sap) {
  typedef __attribute__((ext_vector_type(8))) short short8;
  typedef __attribute__((ext_vector_type(4))) float f32x4;
  union V16 { uint4 u; short8 s; ushort us[8]; };

  __shared__ __align__(16) ushort q_l[16 * 256];   // 8KB: qh slot-rows 0-7, ql 8-15
  __shared__ __align__(16) ushort xbuf[32 * 256];  // 16KB shared x-tile (plane layout)
  __shared__ __align__(16) float scr[4 * 512];     // 8KB QK partials

  int t = threadIdx.x, wid = t >> 6, lane = t & 63;
  int bI = blockIdx.x >> 5, c = blockIdx.x & 31;
  int lm = lane & 15, g = lane >> 4;
  char* xwB = (char*)xbuf;
  char* qB = (char*)q_l;

  // ---- stage q hi/lo planes into rotated plane layout (R7-proven) ----
  {
    const float* qkb = qk + (size_t)bI * (KK * DD);
    int p = t >> 3, e7 = t & 7;
#pragma unroll 1
    for (int s = 0; s < 8; ++s) {
      float qv = qkb[s * 256 + t];
      __hip_bfloat16 hb = __float2bfloat16(qv);
      float lo = qv - __bfloat162float(hb);
      __hip_bfloat16 lb = __float2bfloat16(lo);
      *(ushort*)(qB + s * 512 + (((p + s) & 31) << 4) + e7 * 2) = *(ushort*)&hb;
      *(ushort*)(qB + (s + 8) * 512 + (((p + s + 8) & 31) << 4) + e7 * 2) = *(ushort*)&lb;
    }
  }
  float qbv = qb[bI * 8 + (lane & 7)];

  f32x4 avacc[4];
#pragma unroll
  for (int i = 0; i < 4; ++i) avacc[i] = (f32x4){0.0f, 0.0f, 0.0f, 0.0f};
  float stot = 0.0f;

#pragma unroll 1
  for (int tt = 0; tt < 4; ++tt) {
    int row0 = c * 128 + tt * 32;

    // ---------------- stage tile tt into xbuf ----------------
    if (DO_LN) {
      __syncthreads();  // prev tile consumed (and q_l ready at tt=0)
      int q8 = t & 7, rr = t >> 3;  // rr in 0..31: row within tile
      const float* rp = inp + ((size_t)bI * NN + row0 + rr) * DD + q8 * 4;
      float4 cur[8];
#pragma unroll
      for (int i = 0; i < 8; ++i) cur[i] = *(const float4*)(rp + i * 32);
      float s1 = 0.0f, s2 = 0.0f;
#pragma unroll
      for (int i = 0; i < 8; ++i) {
        s1 += cur[i].x + cur[i].y + cur[i].z + cur[i].w;
        s2 += cur[i].x * cur[i].x + cur[i].y * cur[i].y + cur[i].z * cur[i].z + cur[i].w * cur[i].w;
      }
      s1 += __shfl_xor(s1, 1); s2 += __shfl_xor(s2, 1);
      s1 += __shfl_xor(s1, 2); s2 += __shfl_xor(s2, 2);
      s1 += __shfl_xor(s1, 4); s2 += __shfl_xor(s2, 4);
      float m = s1 * (1.0f / DD);
      float var = s2 * (1.0f / DD) - m * m;
      float rs = rsqrtf(var + LN_EPS);
      int pb = q8 >> 1, hb8 = (q8 & 1) * 8;
#pragma unroll
      for (int i = 0; i < 8; ++i) {
        uint2 wv;
        wv.x = pk2bf((cur[i].x - m) * rs, (cur[i].y - m) * rs);
        wv.y = pk2bf((cur[i].z - m) * rs, (cur[i].w - m) * rs);
        *(uint2*)(xwB + ((4 * i + pb) << 9) + (rr << 4) + hb8) = wv;
      }
      __syncthreads();  // tile image complete
      // coalesced xb writeout (global image == LDS image)
      ushort* xbt = xb_out + ((size_t)bI * NN + row0) * DD;
#pragma unroll
      for (int i = 0; i < 4; ++i)
        *(uint4*)((char*)xbt + i * 4096 + t * 16) = *(const uint4*)(xwB + i * 4096 + t * 16);
    } else {
      __syncthreads();  // prev tile consumed / q_l ready
      const ushort* srcb = xb_in + ((size_t)bI * NN + row0) * DD;
#pragma unroll
      for (int i = 0; i < 4; ++i) {
        __builtin_amdgcn_global_load_lds(
            (__attribute__((address_space(1))) void*)(srcb + i * 2048 + wid * 512 + lane * 8),
            (__attribute__((address_space(3))) void*)(xbuf + i * 2048 + wid * 512), 16, 0, 0);
      }
      asm volatile("s_waitcnt vmcnt(0)" ::: "memory");
      __syncthreads();
    }

    // ---------------- QK partials: wave wid does kk in {2wid, 2wid+1} ----------------
    f32x4 p0 = (f32x4){0.0f, 0.0f, 0.0f, 0.0f}, p1 = (f32x4){0.0f, 0.0f, 0.0f, 0.0f};
#pragma unroll
    for (int kx = 0; kx < 2; ++kx) {
      int ch = (2 * wid + kx) * 4 + g;
      V16 qf, x0, x1;
      qf.u = *(const uint4*)(qB + (lm << 9) + (((ch + lm) & 31) << 4));
      x0.u = *(const uint4*)(xwB + (ch << 9) + (lm << 4));
      x1.u = *(const uint4*)(xwB + (ch << 9) + ((lm + 16) << 4));
      p0 = __builtin_amdgcn_mfma_f32_16x16x32_bf16(x0.s, qf.s, p0, 0, 0, 0);
      p1 = __builtin_amdgcn_mfma_f32_16x16x32_bf16(x1.s, qf.s, p1, 0, 0, 0);
    }
    *(f32x4*)&scr[wid * 512 + lane * 8] = p0;
    *(f32x4*)&scr[wid * 512 + lane * 8 + 4] = p1;
    __syncthreads();

    // ---------------- sum partials (identical in all waves) ----------------
    f32x4 s0 = (f32x4){0.0f, 0.0f, 0.0f, 0.0f}, s1v = (f32x4){0.0f, 0.0f, 0.0f, 0.0f};
#pragma unroll
    for (int w2 = 0; w2 < 4; ++w2) {
      s0 += *(const f32x4*)&scr[w2 * 512 + lane * 8];
      s1v += *(const f32x4*)&scr[w2 * 512 + lane * 8 + 4];
    }

    // ---------------- softmax over slots (R7-proven, rows vectorized) ----------------
    float a0[4], a1[4];
    {
      float lv0[4], lv1[4], mx0[4], mx1[4], ss0[4], ss1[4];
#pragma unroll
      for (int r = 0; r < 4; ++r) {
        lv0[r] = s0[r] + __shfl_xor(s0[r], 8) + qbv;
        lv1[r] = s1v[r] + __shfl_xor(s1v[r], 8) + qbv;
        mx0[r] = lv0[r]; mx1[r] = lv1[r];
      }
#pragma unroll
      for (int off = 1; off <= 4; off <<= 1) {
#pragma unroll
        for (int r = 0; r < 4; ++r) {
          mx0[r] = fmaxf(mx0[r], __shfl_xor(mx0[r], off));
          mx1[r] = fmaxf(mx1[r], __shfl_xor(mx1[r], off));
        }
      }
#pragma unroll
      for (int r = 0; r < 4; ++r) {
        a0[r] = __expf(lv0[r] - mx0[r]);
        a1[r] = __expf(lv1[r] - mx1[r]);
        ss0[r] = a0[r]; ss1[r] = a1[r];
      }
#pragma unroll
      for (int off = 1; off <= 4; off <<= 1) {
#pragma unroll
        for (int r = 0; r < 4; ++r) {
          ss0[r] += __shfl_xor(ss0[r], off);
          ss1[r] += __shfl_xor(ss1[r], off);
        }
      }
#pragma unroll
      for (int r = 0; r < 4; ++r) {
        a0[r] *= __frcp_rn(ss0[r]);
        a1[r] *= __frcp_rn(ss1[r]);
      }
    }
    float sacc = 0.0f;
#pragma unroll
    for (int r = 0; r < 4; ++r) sacc += a0[r] + a1[r];
    sacc += __shfl_xor(sacc, 16);
    sacc += __shfl_xor(sacc, 32);
    stot += sacc;

    // ---------------- pack A-fragment: hi planes (lane&8==0) / lo planes ----------------
    bool lop = (lane & 8) != 0;
    V16 au;
    {
      float t8[8];
#pragma unroll
      for (int e = 0; e < 8; ++e) {
        float av = (e < 4) ? a0[e] : a1[e - 4];
        if (lop) {
          __hip_bfloat16 hb = __float2bfloat16(av);
          av = av - __bfloat162float(hb);
        }
        t8[e] = av;
      }
      au.u = make_uint4(pk2bf(t8[0], t8[1]), pk2bf(t8[2], t8[3]),
                        pk2bf(t8[4], t8[5]), pk2bf(t8[6], t8[7]));
    }

    // ---------------- AV: wave wid owns dc in {4wid..4wid+3}, accumulate ----------------
#pragma unroll
    for (int cc = 0; cc < 4; ++cc) {
      int dc = 4 * wid + cc;
      int d = dc * 16 + lm, dch = d >> 3, d7b = (d & 7) * 2;
      int r0 = 4 * g, r2 = 16 + 4 * g;
      const char* pl = xwB + (dch << 9) + d7b;
      V16 bu;
      bu.u.x = (uint)*(const ushort*)(pl + ((r0 + 0) << 4)) |
               ((uint)*(const ushort*)(pl + ((r0 + 1) << 4)) << 16);
      bu.u.y = (uint)*(const ushort*)(pl + ((r0 + 2) << 4)) |
               ((uint)*(const ushort*)(pl + ((r0 + 3) << 4)) << 16);
      bu.u.z = (uint)*(const ushort*)(pl + ((r2 + 0) << 4)) |
               ((uint)*(const ushort*)(pl + ((r2 + 1) << 4)) << 16);
      bu.u.w = (uint)*(const ushort*)(pl + ((r2 + 2) << 4)) |
               ((uint)*(const ushort*)(pl + ((r2 + 3) << 4)) << 16);
      avacc[cc] = __builtin_amdgcn_mfma_f32_16x16x32_bf16(au.s, bu.s, avacc[cc], 0, 0, 0);
    }
  }

  // ---------------- epilogue: hi+lo combine, direct uxp store ----------------
  size_t obase = ((size_t)(bI * NCHUNK + c)) * (KK * DD);
#pragma unroll
  for (int cc = 0; cc < 4; ++cc) {
#pragma unroll
    for (int r = 0; r < 4; ++r) {
      float v = avacc[cc][r];
      float o = v + __shfl_xor(v, 32);
      if (lane < 32) uxp[obase + (g * 4 + r) * 256 + (4 * wid + cc) * 16 + lm] = o;
    }
  }
  if (wid == 0 && lane < 8) sap[((size_t)(bI * NCHUNK + c)) * KK + lane] = stot;
}

// ---------- Kernel 4: fused slot update, 1 row (b,k) per block, 1024 threads ----------
__global__ __launch_bounds__(1024) void k_fused(const float* __restrict__ slots_in,
                                                const float* __restrict__ uxp,
                                                const float* __restrict__ sap,
                                                const ushort* __restrict__ wb,
                                                const float* __restrict__ bv,
                                                const float* __restrict__ bih, const float* __restrict__ bhh,
                                                const float* __restrict__ gff, const float* __restrict__ bff,
                                                const float* __restrict__ b1, const float* __restrict__ b2,
                                                const float* __restrict__ gs, const float* __restrict__ bs,
                                                const float* __restrict__ bq, const float* __restrict__ bk,
                                                const float* __restrict__ gi, const float* __restrict__ bi,
                                                float* __restrict__ dst,
                                                float* __restrict__ qk_out,
                                                float* __restrict__ qb_out,
                                                int last) {
  const ushort* WG = wb + OFF_G;
  const ushort* W1p = wb + OFF_W1;
  const ushort* W2p = wb + OFF_W2;
  const ushort* WVp = wb + OFF_WV;
  const ushort* WQp = wb + OFF_WQ;
  const ushort* WKp = wb + OFF_WK;

  __shared__ float ux_s[DD], h_s[DD], upd_s[DD], hn_s[DD], ln_s[DD];
  __shared__ float g_s[6][DD];
  __shared__ float hdd_s[HH];
  __shared__ float tmp4_s[4][DD];
  __shared__ float red_s[16];
  __shared__ float sA_s;
  float* tmpH = &tmp4_s[0][0];  // [2][512] alias

  int t = threadIdx.x, d = t & 255, qr = t >> 8;
  int wid = t >> 6, lane = t & 63;
  int r = blockIdx.x, b = r >> 3, k = r & 7;

  // ---- phase 0: reduce 32 attention partials; load h; reduce sA ----
  {
    const float* p = uxp + (((size_t)(b * NCHUNK + qr * 8)) * KK + k) * DD + d;
    float s = 0.0f;
#pragma unroll
    for (int i = 0; i < 8; ++i) s += p[(size_t)i * KK * DD];
    tmp4_s[qr][d] = s;
  }
  if (t < 256) h_s[t] = slots_in[(size_t)r * DD + t];
  if (t >= 960) {
    int c = t - 960;
    float v = (c < NCHUNK) ? sap[((size_t)(b * NCHUNK + c)) * KK + k] : 0.0f;
    v = wave_sum(v);
    if (lane == 0) sA_s = v;
  }
  __syncthreads();
  if (t < 256) ux_s[t] = tmp4_s[0][t] + tmp4_s[1][t] + tmp4_s[2][t] + tmp4_s[3][t];
  __syncthreads();

  // ---- phase 1: upd = WVg.ux + bv'*sA ----
  tmp4_s[qr][d] = gemv_p<256, 64>(WVp, d, qr * 64, ux_s);
  __syncthreads();
  if (t < 256) upd_s[t] = tmp4_s[0][t] + tmp4_s[1][t] + tmp4_s[2][t] + tmp4_s[3][t] + bv[t] * sA_s;
  __syncthreads();

  // ---- phase 2: GRU gates ----
  {
    int g = qr;  // 0..3: ih_r, ih_z, ih_n, hh_r
    const float* src = (g < 3) ? upd_s : h_s;
    float a = gemv_p<256, 256>(WG + (size_t)g * 65536, d, 0, src);
    g_s[g][d] = a + ((g < 3) ? bih[g * 256 + d] : bhh[d]);
    if (t < 512) {
      int g2 = 4 + (t >> 8), j2 = t & 255;  // hh_z, hh_n
      float a2 = gemv_p<256, 256>(WG + (size_t)g2 * 65536, j2, 0, h_s);
      g_s[g2][j2] = a2 + bhh[(g2 - 3) * 256 + j2];
    }
  }
  __syncthreads();
  if (t < 256) {
    float rr = sigmoidf_(g_s[0][t] + g_s[3][t]);
    float zz = sigmoidf_(g_s[1][t] + g_s[4][t]);
    float nn = tanhf(g_s[2][t] + rr * g_s[5][t]);
    hn_s[t] = (1.0f - zz) * nn + zz * h_s[t];
  }
  __syncthreads();

  // ---- phase 3: LN(hn) with ff params ----
  if (t < 256) {
    float v = hn_s[t];
    float sm = wave_sum(v), sq = wave_sum(v * v);
    if (lane == 0) { red_s[wid] = sm; red_s[8 + wid] = sq; }
  }
  __syncthreads();
  if (t < 256) {
    float v = hn_s[t];
    float tot = red_s[0] + red_s[1] + red_s[2] + red_s[3];
    float tot2 = red_s[8] + red_s[9] + red_s[10] + red_s[11];
    float m = tot * (1.0f / DD);
    float var = tot2 * (1.0f / DD) - m * m;
    float rs = rsqrtf(var + LN_EPS);
    ln_s[t] = (v - m) * rs * gff[t] + bff[t];
  }
  __syncthreads();

  // ---- phase 4: hdd = relu(W1.ln + b1) ----
  {
    int o = t & 511, kh = t >> 9;
    tmpH[kh * 512 + o] = gemv_p<512, 128>(W1p, o, kh * 128, ln_s);
  }
  __syncthreads();
  if (t < 512) hdd_s[t] = fmaxf(tmpH[t] + tmpH[512 + t] + b1[t], 0.0f);
  __syncthreads();

  // ---- phase 5: out = hn + W2.hdd + b2 ----
  tmp4_s[qr][d] = gemv_p<256, 128>(W2p, d, qr * 128, hdd_s);
  __syncthreads();
  if (t < 256) {
    float o = hn_s[t] + tmp4_s[0][t] + tmp4_s[1][t] + tmp4_s[2][t] + tmp4_s[3][t] + b2[t];
    dst[(size_t)r * DD + t] = o;
    ux_s[t] = o;  // new slots
  }
  __syncthreads();

  if (!last) {
    // ---- 6a: LN(new slots) with slot params ----
    if (t < 256) {
      float v = ux_s[t];
      float sm = wave_sum(v), sq = wave_sum(v * v);
      if (lane == 0) { red_s[wid] = sm; red_s[8 + wid] = sq; }
    }
    __syncthreads();
    if (t < 256) {
      float v = ux_s[t];
      float tot = red_s[0] + red_s[1] + red_s[2] + red_s[3];
      float tot2 = red_s[8] + red_s[9] + red_s[10] + red_s[11];
      float m = tot * (1.0f / DD);
      float var = tot2 * (1.0f / DD) - m * m;
      float rs = rsqrtf(var + LN_EPS);
      ln_s[t] = (v - m) * rs * gs[t] + bs[t];
    }
    __syncthreads();
    // ---- 6b: q = Wq.ln + bq ----
    tmp4_s[qr][d] = gemv_p<256, 64>(WQp, d, qr * 64, ln_s);
    __syncthreads();
    if (t < 256) {
      float qv = tmp4_s[0][t] + tmp4_s[1][t] + tmp4_s[2][t] + tmp4_s[3][t] + bq[t];
      upd_s[t] = qv;  // q row
      float sb = wave_sum(qv * bk[t]);
      if (lane == 0) red_s[wid] = sb;
    }
    __syncthreads();
    // ---- 6c: qk[j] = SCALE * Wk^T q, with LN-in g/b folded ----
    {
      float a = gemv_p<256, 64>(WKp, d, qr * 64, upd_s);
      tmp4_s[qr][d] = a;
    }
    __syncthreads();
    if (t < 256) {
      float qkv = SCALE * (tmp4_s[0][t] + tmp4_s[1][t] + tmp4_s[2][t] + tmp4_s[3][t]);
      qk_out[(size_t)r * DD + t] = qkv * gi[t];
      float pb2 = wave_sum(qkv * bi[t]);
      if (lane == 0) red_s[8 + wid] = pb2;
    }
    __syncthreads();
    if (t == 0) qb_out[r] = SCALE * (red_s[0] + red_s[1] + red_s[2] + red_s[3]) +
                            red_s[8] + red_s[9] + red_s[10] + red_s[11];
  }
}

extern "C" void kernel_launch(void* const* d_in, const int* in_sizes, int n_in,
                              void* d_out, int out_size, void* d_ws, size_t ws_size,
                              hipStream_t stream) {
  const float* inputs = (const float*)d_in[0];
  const float* slots_init = (const float*)d_in[1];
  const float* ln_in_g = (const float*)d_in[2];
  const float* ln_in_b = (const float*)d_in[3];
  const float* ln_s_g = (const float*)d_in[4];
  const float* ln_s_b = (const float*)d_in[5];
  const float* ln_ff_g = (const float*)d_in[6];
  const float* ln_ff_b = (const float*)d_in[7];
  const float* Wk = (const float*)d_in[8];
  const float* bk = (const float*)d_in[9];
  const float* Wq = (const float*)d_in[10];
  const float* bq = (const float*)d_in[11];
  const float* Wv = (const float*)d_in[12];
  const float* bv = (const float*)d_in[13];
  const float* Wih = (const float*)d_in[14];
  const float* bih = (const float*)d_in[15];
  const float* Whh = (const float*)d_in[16];
  const float* bhh = (const float*)d_in[17];
  const float* W1 = (const float*)d_in[18];
  const float* b1 = (const float*)d_in[19];
  const float* W2 = (const float*)d_in[20];
  const float* b2 = (const float*)d_in[21];
  float* outp = (float*)d_out;

  char* w = (char*)d_ws;
  ushort* xb = (ushort*)w;       w += (size_t)BB * NN * DD * 2;
  float* qk = (float*)w;         w += (size_t)BB * KK * DD * 4;
  float* qb = (float*)w;         w += (size_t)BB * KK * 4;
  float* uxp = (float*)w;        w += (size_t)BB * NCHUNK * KK * DD * 4;
  float* sap = (float*)w;        w += (size_t)BB * NCHUNK * KK * 4;
  float* slots_ws = (float*)w;   w += (size_t)BB * KK * DD * 4;
  ushort* wb = (ushort*)w;       w += (size_t)WB_ELEMS * 2;
  float* bvw = (float*)w;        w += (size_t)DD * 4;

  k_setup<<<G_SETUP, 256, 0, stream>>>(Wih, Whh, W1, W2, Wv, Wq, Wk, wb,
                                       slots_init, ln_s_g, ln_s_b, bq, bk,
                                       ln_in_g, ln_in_b, bv, bvw, qk, qb);

  for (int it = 0; it < 3; ++it) {
    if (it == 0)
      k_attn_t<1><<<BB * NCHUNK, 256, 0, stream>>>(nullptr, xb, inputs, qk, qb, uxp, sap);
    else
      k_attn_t<0><<<BB * NCHUNK, 256, 0, stream>>>(xb, nullptr, nullptr, qk, qb, uxp, sap);
    const float* sin = (it == 0) ? slots_init : slots_ws;
    float* dst = (it == 2) ? outp : slots_ws;
    k_fused<<<BB * KK, 1024, 0, stream>>>(sin, uxp, sap, wb,
                                          bvw, bih, bhh, ln_ff_g, ln_ff_b, b1, b2,
                                          ln_s_g, ln_s_b, bq, bk, ln_in_g, ln_in_b,
                                          dst, qk, qb, (it == 2) ? 1 : 0);
  }
}